// Round 2
// baseline (927.826 us; speedup 1.0000x reference)
//
#include <hip/hip_runtime.h>
#include <hip/hip_bf16.h>
#include <cstdint>
#include <math.h>

using u16 = unsigned short;
typedef __attribute__((ext_vector_type(8))) short bf16x8;
typedef __attribute__((ext_vector_type(4))) float f32x4;

// round-to-nearest-even f32 -> bf16 (values are finite; no NaN path needed)
static __device__ __forceinline__ u16 f2bf(float f) {
    union { float f; unsigned int u; } v; v.f = f;
    return (u16)((v.u + 0x7FFFu + ((v.u >> 16) & 1u)) >> 16);
}

typedef const __attribute__((address_space(1))) unsigned int* gptr_t;
typedef __attribute__((address_space(3))) unsigned int* lptr_t;

static __device__ __forceinline__ void load_lds16(const void* g, void* l) {
    __builtin_amdgcn_global_load_lds((gptr_t)g, (lptr_t)l, 16, 0, 0);
}

// raw barrier: memory clobber (LDS/global ops may not cross) but NO
// sched_barrier pinning — register-only MFMA/VALU schedule stays free.
// (m141 lesson: sched_barrier(0) around every barrier fragments live ranges
// and defeats compiler scheduling — that was round 1's 48% VALUBusy.)
static __device__ __forceinline__ void bar() {
    asm volatile("s_barrier" ::: "memory");
}

// ---------------------------------------------------------------------------
// Kernel 1: transpose + fp32->bf16 cast of the 34 weight matrices.
// Wt slot layout: [0..15] W1_e members, [16] W1_s, [17..32] W2_e, [33] W2_s.
// Each slot is 1024x1024 bf16 stored TRANSPOSED: Wt[n][k] (n = output dim).
// ---------------------------------------------------------------------------
__global__ __launch_bounds__(256)
void wconv(const float* __restrict__ W1e, const float* __restrict__ W1s,
           const float* __restrict__ W2e, const float* __restrict__ W2s,
           u16* __restrict__ Wt)
{
    const int mat = blockIdx.z;
    const float* src;
    if (mat < 17) src = (mat < 16) ? (W1e + (size_t)mat * 1048576) : W1s;
    else {
        const int m2 = mat - 17;
        src = (m2 < 16) ? (W2e + (size_t)m2 * 1048576) : W2s;
    }
    u16* dst = Wt + (size_t)mat * 1048576;

    __shared__ float tile[32][33];
    const int tx = threadIdx.x & 31, ty = threadIdx.x >> 5;  // 32 x 8
    const int c0 = blockIdx.x * 32, r0 = blockIdx.y * 32;

#pragma unroll
    for (int j = 0; j < 32; j += 8)
        tile[ty + j][tx] = src[(size_t)(r0 + ty + j) * 1024 + c0 + tx];
    __syncthreads();
#pragma unroll
    for (int j = 0; j < 32; j += 8)
        dst[(size_t)(c0 + ty + j) * 1024 + r0 + tx] = f2bf(tile[tx][ty + j]);
}

// ---------------------------------------------------------------------------
// Kernel 2: LayerNorm, one wave per row, output bf16 in p-major grouped
// layout Y[p][b][d] so each GEMM slice p sees a dense 2048x1024 A matrix.
// ---------------------------------------------------------------------------
__global__ __launch_bounds__(256)
void ln_kernel(const float* __restrict__ x,
               const float* __restrict__ g_e, const float* __restrict__ b_e,
               const float* __restrict__ g_s, const float* __restrict__ b_s,
               u16* __restrict__ Yg)
{
    const int row  = blockIdx.x * 4 + (threadIdx.x >> 6);   // 0..65535
    const int lane = threadIdx.x & 63;
    const int b = row >> 5, p = row & 31;

    const float4* x4 = (const float4*)(x + (size_t)row * 1024) + lane * 4;
    float4 v[4];
    float sum = 0.f, ssq = 0.f;
#pragma unroll
    for (int i = 0; i < 4; i++) {
        v[i] = x4[i];
        sum += v[i].x + v[i].y + v[i].z + v[i].w;
        ssq += v[i].x * v[i].x + v[i].y * v[i].y + v[i].z * v[i].z + v[i].w * v[i].w;
    }
#pragma unroll
    for (int off = 32; off > 0; off >>= 1) {
        sum += __shfl_xor(sum, off);
        ssq += __shfl_xor(ssq, off);
    }
    const float mean = sum * (1.0f / 1024.0f);
    const float var  = ssq * (1.0f / 1024.0f) - mean * mean;   // biased, like jnp.var
    const float rstd = rsqrtf(var + 1e-5f);

    const float4* g4 = (const float4*)((p < 16) ? (g_e + p * 1024) : g_s) + lane * 4;
    const float4* b4 = (const float4*)((p < 16) ? (b_e + p * 1024) : b_s) + lane * 4;

    __attribute__((aligned(16))) u16 o[16];
#pragma unroll
    for (int i = 0; i < 4; i++) {
        const float4 g = g4[i], bb = b4[i];
        o[i * 4 + 0] = f2bf((v[i].x - mean) * rstd * g.x + bb.x);
        o[i * 4 + 1] = f2bf((v[i].y - mean) * rstd * g.y + bb.y);
        o[i * 4 + 2] = f2bf((v[i].z - mean) * rstd * g.z + bb.z);
        o[i * 4 + 3] = f2bf((v[i].w - mean) * rstd * g.w + bb.w);
    }
    u16* dst = Yg + ((size_t)p * 2048 + b) * 1024 + lane * 16;
    ((uint4*)dst)[0] = ((const uint4*)o)[0];
    ((uint4*)dst)[1] = ((const uint4*)o)[1];
}

// ---------------------------------------------------------------------------
// Kernels 3/4: batched bf16 GEMM, 256x256 tile, BK=64, 512 thr (8 waves 2Mx4N),
// 4-phase-per-K-tile pipelined schedule with counted vmcnt (T3+T4), XOR bank
// swizzle on the LDS tiles (T2, both-sides: pre-swizzled global src for
// global_load_lds + swizzled ds_read), setprio around MFMA clusters (T5),
// XCD-chunked block remap (T1).
//
// LDS: lds[slot2][A/B][half2][128*64 bf16] = 128 KiB. A K-tile's A (256x64)
// = 2 halves of 128 rows; same for B (Wt is [n][k] so B rows are n).
// Swizzle: 16B granule at LDS offset g*16 holds logical (row r=g>>3,
// col-slot c=(g&7)^(r&7)).  ds_read slot for (kk,kq,row): (kk*4+kq)^(row&7).
//
// Stage schedule per iter t (slot sl=t&1, other ot): ph0 stages A-half0(t+1)
// into ot (freed end of iter t-1), ph1 A-half1(t+1), ph2 B-half0(t+2) into sl
// (B of slot sl fully read by end of ph1), ph3 B-half1(t+2).  One
// s_waitcnt vmcnt(4) per iter: retires A(t+1)+B(t+1), leaves B(t+2) in flight.
// ---------------------------------------------------------------------------
static __device__ __forceinline__ void stage2(const u16* gb, u16* lb,
                                              const size_t* sg, const int* sl) {
    load_lds16(gb + sg[0], lb + sl[0]);
    load_lds16(gb + sg[1], lb + sl[1]);
}

static __device__ __forceinline__ bf16x8 ld_frag(const u16* h, int row, int slot) {
    return *(const bf16x8*)(h + row * 64 + slot * 8);
}

#define MFMA_BF16 __builtin_amdgcn_mfma_f32_16x16x32_bf16

template <int STAGE>
__global__ __launch_bounds__(512, 2)
void gemm_ffn(const u16* __restrict__ Abase, const u16* __restrict__ Wt,
              const float* __restrict__ bias_e, const float* __restrict__ bias_s,
              u16* __restrict__ Hout, float* __restrict__ Fout)
{
    // T1: XCD-chunked bijective remap (1024 blocks, 1024%8==0): XCD k gets a
    // contiguous run of 128 vtiles = 4 whole p-slices -> W slot L2-resident.
    const int d   = blockIdx.x;
    const int vid = (d & 7) * 128 + (d >> 3);
    const int p   = vid >> 5;
    const int rem = vid & 31;
    const int m0  = (rem >> 2) * 256;   // 8 m-tiles
    const int n0  = (rem & 3) * 256;    // 4 n-tiles

    const u16* Ap = Abase + (size_t)p * (2048u * 1024u);
    const u16* Bp = Wt + (size_t)((p < 16) ? p : 16) * (1024u * 1024u);
    const float* bias = (p < 16) ? (bias_e + p * 1024) : bias_s;

    __shared__ u16 lds[2][2][2][8192];   // [slot][A=0/B=1][half][128*64]

    const int tid = threadIdx.x;
    const int w = tid >> 6, l = tid & 63;
    const int lr = l & 15, kq = l >> 4;
    const int wmh = w >> 2;              // wave's A half (0/1): 128 rows of M
    const int wq  = w & 3;               // wave's N quadrant (64 cols)
    const int wnh = wq >> 1;             // wave's B half
    const int bnb = (wq & 1) * 64;       // row base inside B half
    const int sl0 = kq ^ (lr & 7);       // swizzled ds_read slot, kk=0
    const int sl1 = sl0 ^ 4;             // kk=1

    // per-thread staging offsets (u16 units), computed once
    size_t sg[2]; int slo[2];
#pragma unroll
    for (int j = 0; j < 2; j++) {
        const int g = tid + j * 512;     // granule 0..1023 (16 B each)
        const int r = g >> 3;            // row 0..127
        const int c = (g & 7) ^ (r & 7); // inverse-swizzled global col slot
        sg[j]  = (size_t)r * 1024 + c * 8;
        slo[j] = g * 8;
    }

    f32x4 acc[8][4];
#pragma unroll
    for (int i = 0; i < 8; i++)
#pragma unroll
        for (int j = 0; j < 4; j++)
            acc[i][j] = (f32x4){0.f, 0.f, 0.f, 0.f};

    // prologue: K-tile0 (A0,A1,B0,B1 -> slot0), K-tile1 (B0,B1 -> slot1)
    stage2(Ap + (size_t)(m0      ) * 1024,      &lds[0][0][0][0], sg, slo);
    stage2(Ap + (size_t)(m0 + 128) * 1024,      &lds[0][0][1][0], sg, slo);
    stage2(Bp + (size_t)(n0      ) * 1024,      &lds[0][1][0][0], sg, slo);
    stage2(Bp + (size_t)(n0 + 128) * 1024,      &lds[0][1][1][0], sg, slo);
    stage2(Bp + (size_t)(n0      ) * 1024 + 64, &lds[1][1][0][0], sg, slo);
    stage2(Bp + (size_t)(n0 + 128) * 1024 + 64, &lds[1][1][1][0], sg, slo);
    asm volatile("s_waitcnt vmcnt(4)" ::: "memory");   // K-tile0 landed
    bar();

    bf16x8 a[4][2], b[4][2];

    for (int t = 0; t < 16; ++t) {
        const int sl = t & 1, ot = sl ^ 1;
        const u16* hA = &lds[sl][0][wmh][0];
        const u16* hB = &lds[sl][1][wnh][0];

        // ---- phase 0: read A m0-3 + B n0-1; stage A-half0(t+1) ----
#pragma unroll
        for (int i = 0; i < 4; ++i) {
            a[i][0] = ld_frag(hA, i * 16 + lr, sl0);
            a[i][1] = ld_frag(hA, i * 16 + lr, sl1);
        }
#pragma unroll
        for (int j = 0; j < 2; ++j) {
            b[j][0] = ld_frag(hB, bnb + j * 16 + lr, sl0);
            b[j][1] = ld_frag(hB, bnb + j * 16 + lr, sl1);
        }
        if (t < 15)
            stage2(Ap + (size_t)m0 * 1024 + (t + 1) * 64, &lds[ot][0][0][0], sg, slo);
        bar();
        __builtin_amdgcn_s_setprio(1);
#pragma unroll
        for (int i = 0; i < 4; ++i)
#pragma unroll
            for (int j = 0; j < 2; ++j) {
                acc[i][j] = MFMA_BF16(a[i][0], b[j][0], acc[i][j], 0, 0, 0);
                acc[i][j] = MFMA_BF16(a[i][1], b[j][1], acc[i][j], 0, 0, 0);
            }
        __builtin_amdgcn_s_setprio(0);
        bar();

        // ---- phase 1: read B n2-3; stage A-half1(t+1) ----
#pragma unroll
        for (int j = 0; j < 2; ++j) {
            b[2 + j][0] = ld_frag(hB, bnb + (2 + j) * 16 + lr, sl0);
            b[2 + j][1] = ld_frag(hB, bnb + (2 + j) * 16 + lr, sl1);
        }
        if (t < 15)
            stage2(Ap + (size_t)(m0 + 128) * 1024 + (t + 1) * 64, &lds[ot][0][1][0], sg, slo);
        bar();
        __builtin_amdgcn_s_setprio(1);
#pragma unroll
        for (int i = 0; i < 4; ++i)
#pragma unroll
            for (int j = 0; j < 2; ++j) {
                acc[i][2 + j] = MFMA_BF16(a[i][0], b[2 + j][0], acc[i][2 + j], 0, 0, 0);
                acc[i][2 + j] = MFMA_BF16(a[i][1], b[2 + j][1], acc[i][2 + j], 0, 0, 0);
            }
        __builtin_amdgcn_s_setprio(0);
        bar();

        // ---- phase 2: read A m4-7; stage B-half0(t+2) ----
#pragma unroll
        for (int i = 0; i < 4; ++i) {
            a[i][0] = ld_frag(hA, (4 + i) * 16 + lr, sl0);
            a[i][1] = ld_frag(hA, (4 + i) * 16 + lr, sl1);
        }
        if (t < 14)
            stage2(Bp + (size_t)n0 * 1024 + (t + 2) * 64, &lds[sl][1][0][0], sg, slo);
        bar();
        __builtin_amdgcn_s_setprio(1);
#pragma unroll
        for (int i = 0; i < 4; ++i)
#pragma unroll
            for (int j = 0; j < 2; ++j) {
                acc[4 + i][j] = MFMA_BF16(a[i][0], b[j][0], acc[4 + i][j], 0, 0, 0);
                acc[4 + i][j] = MFMA_BF16(a[i][1], b[j][1], acc[4 + i][j], 0, 0, 0);
            }
        __builtin_amdgcn_s_setprio(0);
        bar();

        // ---- phase 3: stage B-half1(t+2); MFMA Q11; counted drain ----
        if (t < 14)
            stage2(Bp + (size_t)(n0 + 128) * 1024 + (t + 2) * 64, &lds[sl][1][1][0], sg, slo);
        bar();
        __builtin_amdgcn_s_setprio(1);
#pragma unroll
        for (int i = 0; i < 4; ++i)
#pragma unroll
            for (int j = 0; j < 2; ++j) {
                acc[4 + i][2 + j] = MFMA_BF16(a[i][0], b[2 + j][0], acc[4 + i][2 + j], 0, 0, 0);
                acc[4 + i][2 + j] = MFMA_BF16(a[i][1], b[2 + j][1], acc[4 + i][2 + j], 0, 0, 0);
            }
        __builtin_amdgcn_s_setprio(0);
        if (t < 14) asm volatile("s_waitcnt vmcnt(4)" ::: "memory");
        else        asm volatile("s_waitcnt vmcnt(0)" ::: "memory");
        bar();
    }

    // ---- epilogue ----
    float bv[4];
#pragma unroll
    for (int j = 0; j < 4; ++j) bv[j] = bias[n0 + wq * 64 + j * 16 + lr];

#pragma unroll
    for (int mi = 0; mi < 8; ++mi) {
        const int rbase = m0 + wmh * 128 + mi * 16 + kq * 4;
#pragma unroll
        for (int r = 0; r < 4; ++r) {
            const int row = rbase + r;   // b index
#pragma unroll
            for (int nj = 0; nj < 4; ++nj) {
                const int col = n0 + wq * 64 + nj * 16 + lr;
                float v2 = acc[mi][nj][r] + bv[nj];
                if (STAGE == 1) {
                    v2 = 0.5f * v2 * (1.0f + erff(v2 * 0.70710678118654752f));  // exact gelu
                    Hout[(size_t)p * (2048u * 1024u) + (size_t)row * 1024 + col] = f2bf(v2);
                } else {
                    Fout[((size_t)row * 32 + p) * 1024 + col] = v2;
                }
            }
        }
    }
}

// ---------------------------------------------------------------------------
extern "C" void kernel_launch(void* const* d_in, const int* in_sizes, int n_in,
                              void* d_out, int out_size, void* d_ws, size_t ws_size,
                              hipStream_t stream)
{
    const float* x    = (const float*)d_in[0];
    const float* g_e  = (const float*)d_in[1];
    const float* b_e  = (const float*)d_in[2];
    const float* W1_e = (const float*)d_in[3];
    const float* b1_e = (const float*)d_in[4];
    const float* W2_e = (const float*)d_in[5];
    const float* b2_e = (const float*)d_in[6];
    const float* g_s  = (const float*)d_in[7];
    const float* b_s  = (const float*)d_in[8];
    const float* W1_s = (const float*)d_in[9];
    const float* b1_s = (const float*)d_in[10];
    const float* W2_s = (const float*)d_in[11];
    const float* b2_s = (const float*)d_in[12];
    float* out = (float*)d_out;

    // ws layout: Wt (34 * 1M bf16 = 68 MB) | Y (32*2048*1024 bf16 = 134 MB)
    //            | H (134 MB)  -> total ~340 MB
    u16* Wt = (u16*)d_ws;
    u16* Yg = Wt + (size_t)34 * 1024 * 1024;
    u16* Hg = Yg + (size_t)32 * 2048 * 1024;

    wconv<<<dim3(32, 32, 34), 256, 0, stream>>>(W1_e, W1_s, W2_e, W2_s, Wt);
    ln_kernel<<<16384, 256, 0, stream>>>(x, g_e, b_e, g_s, b_s, Yg);
    gemm_ffn<1><<<dim3(1024), 512, 0, stream>>>(Yg, Wt, b1_e, b1_s, Hg, nullptr);
    gemm_ffn<2><<<dim3(1024), 512, 0, stream>>>(Hg, Wt + (size_t)17 * 1024 * 1024,
                                                b2_e, b2_s, nullptr, out);
}

// Round 3
// 887.659 us; speedup vs baseline: 1.0453x; 1.0453x over previous
//
#include <hip/hip_runtime.h>
#include <hip/hip_bf16.h>
#include <cstdint>
#include <math.h>

using u16 = unsigned short;
typedef __attribute__((ext_vector_type(8))) short bf16x8;
typedef __attribute__((ext_vector_type(4))) float f32x4;
typedef __attribute__((ext_vector_type(4))) unsigned short u16x4;

// round-to-nearest-even f32 -> bf16 (values are finite; no NaN path needed)
static __device__ __forceinline__ u16 f2bf(float f) {
    union { float f; unsigned int u; } v; v.f = f;
    return (u16)((v.u + 0x7FFFu + ((v.u >> 16) & 1u)) >> 16);
}

typedef const __attribute__((address_space(1))) unsigned int* gptr_t;
typedef __attribute__((address_space(3))) unsigned int* lptr_t;

static __device__ __forceinline__ void load_lds16(const void* g, void* l) {
    __builtin_amdgcn_global_load_lds((gptr_t)g, (lptr_t)l, 16, 0, 0);
}

// pinned barrier (R1 structure — best bench so far): sched_barrier fences so
// LDS reads / stage issues cannot migrate across the phase boundary.
static __device__ __forceinline__ void bar_pin() {
    __builtin_amdgcn_sched_barrier(0);
    asm volatile("s_barrier" ::: "memory");
    __builtin_amdgcn_sched_barrier(0);
}
// m201 ingredient: drain ALL ds_reads once, right after the pre-MFMA barrier,
// so the 16-MFMA cluster runs with no interleaved lgkm waits.
static __device__ __forceinline__ void wait_lds0() {
    asm volatile("s_waitcnt lgkmcnt(0)" ::: "memory");
    __builtin_amdgcn_sched_barrier(0);
}

// ---------------------------------------------------------------------------
// Kernel 1 (fused prep): blocks [0, 34816) transpose+cast the 34 weight
// matrices; blocks [34816, 51200) do LayerNorm. Fusing lets the two
// independent BW-bound producers overlap instead of serializing.
//
// Wt slot layout: [0..15] W1_e, [16] W1_s, [17..32] W2_e, [33] W2_s.
// Each slot is 1024x1024 bf16 stored TRANSPOSED: Wt[n][k].
// LN output: bf16 p-major grouped Y[p][b][d] (dense 2048x1024 per GEMM slice).
// ---------------------------------------------------------------------------
__global__ __launch_bounds__(256)
void prep(const float* __restrict__ W1e, const float* __restrict__ W1s,
          const float* __restrict__ W2e, const float* __restrict__ W2s,
          const float* __restrict__ x,
          const float* __restrict__ g_e, const float* __restrict__ b_e,
          const float* __restrict__ g_s, const float* __restrict__ b_s,
          u16* __restrict__ Wt, u16* __restrict__ Yg)
{
    const int id = blockIdx.x;
    if (id < 34816) {
        // ---- weight transpose + cast ----
        const int mat = id >> 10;            // 0..33
        const int rr  = id & 1023;
        const int c0  = (rr & 31) * 32, r0 = (rr >> 5) * 32;
        const float* src;
        if (mat < 17) src = (mat < 16) ? (W1e + (size_t)mat * 1048576) : W1s;
        else {
            const int m2 = mat - 17;
            src = (m2 < 16) ? (W2e + (size_t)m2 * 1048576) : W2s;
        }
        u16* dst = Wt + (size_t)mat * 1048576;

        __shared__ float tile[32][33];
        const int tx = threadIdx.x & 31, ty = threadIdx.x >> 5;  // 32 x 8
#pragma unroll
        for (int j = 0; j < 32; j += 8)
            tile[ty + j][tx] = src[(size_t)(r0 + ty + j) * 1024 + c0 + tx];
        __syncthreads();

        // packed 8B transposed stores: thread (q, oc) writes tile[q*4..q*4+3][oc]
        const int q  = threadIdx.x & 7;      // src-row quad
        const int oc = threadIdx.x >> 3;     // src col = dst row (0..31)
        u16x4 o4;
#pragma unroll
        for (int j = 0; j < 4; j++) o4[j] = f2bf(tile[q * 4 + j][oc]);
        *(u16x4*)(dst + (size_t)(c0 + oc) * 1024 + r0 + q * 4) = o4;
    } else {
        // ---- LayerNorm, one wave per row, lane-contiguous accesses ----
        const int row  = (id - 34816) * 4 + (threadIdx.x >> 6);   // 0..65535
        const int lane = threadIdx.x & 63;
        const int b = row >> 5, p = row & 31;

        const float4* x4 = (const float4*)(x + (size_t)row * 1024);
        float4 v[4];
        float sum = 0.f, ssq = 0.f;
#pragma unroll
        for (int i = 0; i < 4; i++) {
            v[i] = x4[lane + 64 * i];        // per-instruction coalesced (1 KB)
            sum += v[i].x + v[i].y + v[i].z + v[i].w;
            ssq += v[i].x * v[i].x + v[i].y * v[i].y + v[i].z * v[i].z + v[i].w * v[i].w;
        }
#pragma unroll
        for (int off = 32; off > 0; off >>= 1) {
            sum += __shfl_xor(sum, off);
            ssq += __shfl_xor(ssq, off);
        }
        const float mean = sum * (1.0f / 1024.0f);
        const float var  = ssq * (1.0f / 1024.0f) - mean * mean;   // biased, like jnp.var
        const float rstd = rsqrtf(var + 1e-5f);

        const float4* g4 = (const float4*)((p < 16) ? (g_e + p * 1024) : g_s);
        const float4* b4 = (const float4*)((p < 16) ? (b_e + p * 1024) : b_s);
        u16* dst = Yg + ((size_t)p * 2048 + b) * 1024;

#pragma unroll
        for (int i = 0; i < 4; i++) {
            const float4 g = g4[lane + 64 * i], bb = b4[lane + 64 * i];
            u16x4 o;
            o[0] = f2bf((v[i].x - mean) * rstd * g.x + bb.x);
            o[1] = f2bf((v[i].y - mean) * rstd * g.y + bb.y);
            o[2] = f2bf((v[i].z - mean) * rstd * g.z + bb.z);
            o[3] = f2bf((v[i].w - mean) * rstd * g.w + bb.w);
            *(u16x4*)(dst + lane * 4 + i * 256) = o;   // 8B lane-contiguous
        }
    }
}

// ---------------------------------------------------------------------------
// Kernels 2/3: batched bf16 GEMM, 256x256 tile, BK=64, 512 thr (8 waves 2Mx4N),
// 4-phase-per-K-tile pipelined schedule with counted vmcnt (T3+T4), XOR bank
// swizzle (T2, both-sides), setprio around MFMA clusters (T5), XCD-chunked
// block remap (T1), pinned phase boundaries + post-barrier lgkmcnt(0) drain
// (m201-exact phase shape).
//
// LDS: lds[slot2][A/B][half2][128*64 bf16] = 128 KiB.
// Swizzle: granule g*16B holds logical (row r=g>>3, col-slot c=(g&7)^(r&7));
// ds_read slot for (kk,kq,row): (kk*4+kq)^(row&7).
//
// Stage schedule per iter t (slot sl=t&1, other ot): ph0 A-half0(t+1)->ot,
// ph1 A-half1(t+1)->ot, ph2 B-half0(t+2)->sl, ph3 B-half1(t+2)->sl.
// One s_waitcnt vmcnt(4) per iter: retires B(t+1)+A(t+1), leaves B(t+2).
// ---------------------------------------------------------------------------
static __device__ __forceinline__ void stage2(const u16* gb, u16* lb,
                                              const size_t* sg, const int* sl) {
    load_lds16(gb + sg[0], lb + sl[0]);
    load_lds16(gb + sg[1], lb + sl[1]);
}

static __device__ __forceinline__ bf16x8 ld_frag(const u16* h, int row, int slot) {
    return *(const bf16x8*)(h + row * 64 + slot * 8);
}

#define MFMA_BF16 __builtin_amdgcn_mfma_f32_16x16x32_bf16

template <int STAGE>
__global__ __launch_bounds__(512, 2)
void gemm_ffn(const u16* __restrict__ Abase, const u16* __restrict__ Wt,
              const float* __restrict__ bias_e, const float* __restrict__ bias_s,
              u16* __restrict__ Hout, float* __restrict__ Fout)
{
    // T1: XCD-chunked bijective remap (1024 blocks, 1024%8==0).
    const int d   = blockIdx.x;
    const int vid = (d & 7) * 128 + (d >> 3);
    const int p   = vid >> 5;
    const int rem = vid & 31;
    const int m0  = (rem >> 2) * 256;   // 8 m-tiles
    const int n0  = (rem & 3) * 256;    // 4 n-tiles

    const u16* Ap = Abase + (size_t)p * (2048u * 1024u);
    const u16* Bp = Wt + (size_t)((p < 16) ? p : 16) * (1024u * 1024u);
    const float* bias = (p < 16) ? (bias_e + p * 1024) : bias_s;

    __shared__ u16 lds[2][2][2][8192];   // [slot][A=0/B=1][half][128*64]

    const int tid = threadIdx.x;
    const int w = tid >> 6, l = tid & 63;
    const int lr = l & 15, kq = l >> 4;
    const int wmh = w >> 2;              // wave's A half (0/1): 128 rows of M
    const int wq  = w & 3;               // wave's N quadrant (64 cols)
    const int wnh = wq >> 1;             // wave's B half
    const int bnb = (wq & 1) * 64;       // row base inside B half
    const int sl0 = kq ^ (lr & 7);       // swizzled ds_read slot, kk=0
    const int sl1 = sl0 ^ 4;             // kk=1

    // per-thread staging offsets (u16 units), computed once
    size_t sg[2]; int slo[2];
#pragma unroll
    for (int j = 0; j < 2; j++) {
        const int g = tid + j * 512;     // granule 0..1023 (16 B each)
        const int r = g >> 3;            // row 0..127
        const int c = (g & 7) ^ (r & 7); // inverse-swizzled global col slot
        sg[j]  = (size_t)r * 1024 + c * 8;
        slo[j] = g * 8;
    }

    f32x4 acc[8][4];
#pragma unroll
    for (int i = 0; i < 8; i++)
#pragma unroll
        for (int j = 0; j < 4; j++)
            acc[i][j] = (f32x4){0.f, 0.f, 0.f, 0.f};

    // prologue: K-tile0 (A0,A1,B0,B1 -> slot0), K-tile1 (B0,B1 -> slot1)
    stage2(Ap + (size_t)(m0      ) * 1024,      &lds[0][0][0][0], sg, slo);
    stage2(Ap + (size_t)(m0 + 128) * 1024,      &lds[0][0][1][0], sg, slo);
    stage2(Bp + (size_t)(n0      ) * 1024,      &lds[0][1][0][0], sg, slo);
    stage2(Bp + (size_t)(n0 + 128) * 1024,      &lds[0][1][1][0], sg, slo);
    stage2(Bp + (size_t)(n0      ) * 1024 + 64, &lds[1][1][0][0], sg, slo);
    stage2(Bp + (size_t)(n0 + 128) * 1024 + 64, &lds[1][1][1][0], sg, slo);
    asm volatile("s_waitcnt vmcnt(4)" ::: "memory");   // K-tile0 landed
    bar_pin();

    bf16x8 a[4][2], b[4][2];

    for (int t = 0; t < 16; ++t) {
        const int sl = t & 1, ot = sl ^ 1;
        const u16* hA = &lds[sl][0][wmh][0];
        const u16* hB = &lds[sl][1][wnh][0];

        // ---- phase 0: read A m0-3 + B n0-1; stage A-half0(t+1) ----
#pragma unroll
        for (int i = 0; i < 4; ++i) {
            a[i][0] = ld_frag(hA, i * 16 + lr, sl0);
            a[i][1] = ld_frag(hA, i * 16 + lr, sl1);
        }
#pragma unroll
        for (int j = 0; j < 2; ++j) {
            b[j][0] = ld_frag(hB, bnb + j * 16 + lr, sl0);
            b[j][1] = ld_frag(hB, bnb + j * 16 + lr, sl1);
        }
        if (t < 15)
            stage2(Ap + (size_t)m0 * 1024 + (t + 1) * 64, &lds[ot][0][0][0], sg, slo);
        bar_pin();
        wait_lds0();
        __builtin_amdgcn_s_setprio(1);
#pragma unroll
        for (int i = 0; i < 4; ++i)
#pragma unroll
            for (int j = 0; j < 2; ++j) {
                acc[i][j] = MFMA_BF16(a[i][0], b[j][0], acc[i][j], 0, 0, 0);
                acc[i][j] = MFMA_BF16(a[i][1], b[j][1], acc[i][j], 0, 0, 0);
            }
        __builtin_amdgcn_s_setprio(0);
        bar_pin();

        // ---- phase 1: read B n2-3; stage A-half1(t+1) ----
#pragma unroll
        for (int j = 0; j < 2; ++j) {
            b[2 + j][0] = ld_frag(hB, bnb + (2 + j) * 16 + lr, sl0);
            b[2 + j][1] = ld_frag(hB, bnb + (2 + j) * 16 + lr, sl1);
        }
        if (t < 15)
            stage2(Ap + (size_t)(m0 + 128) * 1024 + (t + 1) * 64, &lds[ot][0][1][0], sg, slo);
        bar_pin();
        wait_lds0();
        __builtin_amdgcn_s_setprio(1);
#pragma unroll
        for (int i = 0; i < 4; ++i)
#pragma unroll
            for (int j = 0; j < 2; ++j) {
                acc[i][2 + j] = MFMA_BF16(a[i][0], b[2 + j][0], acc[i][2 + j], 0, 0, 0);
                acc[i][2 + j] = MFMA_BF16(a[i][1], b[2 + j][1], acc[i][2 + j], 0, 0, 0);
            }
        __builtin_amdgcn_s_setprio(0);
        bar_pin();

        // ---- phase 2: read A m4-7; stage B-half0(t+2) ----
#pragma unroll
        for (int i = 0; i < 4; ++i) {
            a[i][0] = ld_frag(hA, (4 + i) * 16 + lr, sl0);
            a[i][1] = ld_frag(hA, (4 + i) * 16 + lr, sl1);
        }
        if (t < 14)
            stage2(Bp + (size_t)n0 * 1024 + (t + 2) * 64, &lds[sl][1][0][0], sg, slo);
        bar_pin();
        wait_lds0();
        __builtin_amdgcn_s_setprio(1);
#pragma unroll
        for (int i = 0; i < 4; ++i)
#pragma unroll
            for (int j = 0; j < 2; ++j) {
                acc[4 + i][j] = MFMA_BF16(a[i][0], b[j][0], acc[4 + i][j], 0, 0, 0);
                acc[4 + i][j] = MFMA_BF16(a[i][1], b[j][1], acc[4 + i][j], 0, 0, 0);
            }
        __builtin_amdgcn_s_setprio(0);
        bar_pin();

        // ---- phase 3: stage B-half1(t+2); MFMA Q11; counted drain ----
        if (t < 14)
            stage2(Bp + (size_t)(n0 + 128) * 1024 + (t + 2) * 64, &lds[sl][1][1][0], sg, slo);
        bar_pin();
        __builtin_amdgcn_s_setprio(1);
#pragma unroll
        for (int i = 0; i < 4; ++i)
#pragma unroll
            for (int j = 0; j < 2; ++j) {
                acc[4 + i][2 + j] = MFMA_BF16(a[i][0], b[2 + j][0], acc[4 + i][2 + j], 0, 0, 0);
                acc[4 + i][2 + j] = MFMA_BF16(a[i][1], b[2 + j][1], acc[4 + i][2 + j], 0, 0, 0);
            }
        __builtin_amdgcn_s_setprio(0);
        if (t < 14) asm volatile("s_waitcnt vmcnt(4)" ::: "memory");
        else        asm volatile("s_waitcnt vmcnt(0)" ::: "memory");
        bar_pin();
    }

    // ---- epilogue ----
    float bv[4];
#pragma unroll
    for (int j = 0; j < 4; ++j) bv[j] = bias[n0 + wq * 64 + j * 16 + lr];

#pragma unroll
    for (int mi = 0; mi < 8; ++mi) {
        const int rbase = m0 + wmh * 128 + mi * 16 + kq * 4;
#pragma unroll
        for (int r = 0; r < 4; ++r) {
            const int row = rbase + r;   // b index
#pragma unroll
            for (int nj = 0; nj < 4; ++nj) {
                const int col = n0 + wq * 64 + nj * 16 + lr;
                float v2 = acc[mi][nj][r] + bv[nj];
                if (STAGE == 1) {
                    v2 = 0.5f * v2 * (1.0f + erff(v2 * 0.70710678118654752f));  // exact gelu
                    Hout[(size_t)p * (2048u * 1024u) + (size_t)row * 1024 + col] = f2bf(v2);
                } else {
                    Fout[((size_t)row * 32 + p) * 1024 + col] = v2;
                }
            }
        }
    }
}

// ---------------------------------------------------------------------------
extern "C" void kernel_launch(void* const* d_in, const int* in_sizes, int n_in,
                              void* d_out, int out_size, void* d_ws, size_t ws_size,
                              hipStream_t stream)
{
    const float* x    = (const float*)d_in[0];
    const float* g_e  = (const float*)d_in[1];
    const float* b_e  = (const float*)d_in[2];
    const float* W1_e = (const float*)d_in[3];
    const float* b1_e = (const float*)d_in[4];
    const float* W2_e = (const float*)d_in[5];
    const float* b2_e = (const float*)d_in[6];
    const float* g_s  = (const float*)d_in[7];
    const float* b_s  = (const float*)d_in[8];
    const float* W1_s = (const float*)d_in[9];
    const float* b1_s = (const float*)d_in[10];
    const float* W2_s = (const float*)d_in[11];
    const float* b2_s = (const float*)d_in[12];
    float* out = (float*)d_out;

    // ws layout: Wt (34 * 1M bf16 = 68 MB) | Y (32*2048*1024 bf16 = 134 MB)
    //            | H (134 MB)  -> total ~340 MB
    u16* Wt = (u16*)d_ws;
    u16* Yg = Wt + (size_t)34 * 1024 * 1024;
    u16* Hg = Yg + (size_t)32 * 2048 * 1024;

    prep<<<dim3(51200), 256, 0, stream>>>(W1_e, W1_s, W2_e, W2_s,
                                          x, g_e, b_e, g_s, b_s, Wt, Yg);
    gemm_ffn<1><<<dim3(1024), 512, 0, stream>>>(Yg, Wt, b1_e, b1_s, Hg, nullptr);
    gemm_ffn<2><<<dim3(1024), 512, 0, stream>>>(Hg, Wt + (size_t)17 * 1024 * 1024,
                                                b2_e, b2_s, nullptr, out);
}